// Round 6
// baseline (321.670 us; speedup 1.0000x reference)
//
#include <hip/hip_runtime.h>
#include <hip/hip_bf16.h>

// MDTA: LN -> 1x1 conv (QKV) -> dw3x3 -> spatial attention (N=4096, d=24, 8 heads) -> proj + residual
// Round 17: flash TLP fix. R16's register-P flash showed Occupancy=31.8%, MfmaUtil=13.7%,
// VALU=33% -> latency-bound with grid-limited TLP (1024 blocks = 4 blocks/CU; VGPR=64+LDS=0
// would allow 8). NSPLIT 8->16: 2048 blocks = 8 blocks/CU = 32 waves/CU (launch_bounds(256,8)
// pins VGPR<=64). opart/lpart double (37MB ws; harness ws >=268MB per fill-kernel WRITE_SIZE).
// gemm_proj combine loops over 16 partials (L2-resident, +~1us). Flash datapath, ln_qkv,
// dwconv unchanged from R16 (passed, absmax 0.0625).

typedef __bf16 bf16;
typedef __bf16 bf16x2 __attribute__((ext_vector_type(2)));
typedef __bf16 bf16x4 __attribute__((ext_vector_type(4)));
typedef __bf16 bf16x8 __attribute__((ext_vector_type(8)));
typedef float f32x4 __attribute__((ext_vector_type(4)));

#define C_DIM 192
#define N_PIX 4096
#define HEADS 8
#define DHEAD 24
#define DPAD 32
#define C3 576
#define NSPLIT 16

__device__ inline float fast_exp2(float x) {
#if __has_builtin(__builtin_amdgcn_exp2f)
    return __builtin_amdgcn_exp2f(x);
#else
    return exp2f(x);
#endif
}

__device__ inline f32x4 mfma16(bf16x8 a, bf16x8 b, f32x4 c) {
    return __builtin_amdgcn_mfma_f32_16x16x32_bf16(a, b, c, 0, 0, 0);
}

// ---------------- fused LN + QKV GEMM (64x64 tile): qkv[576,4096] = wqkv[576,192] * LN(x)[4096,192]^T ----------------
__global__ __launch_bounds__(256) void ln_qkv(const float* __restrict__ x,
                                              const float* __restrict__ gamma,
                                              const float* __restrict__ beta,
                                              const float* __restrict__ wqkv,
                                              bf16* __restrict__ qkvb,
                                              float* __restrict__ maxk2) {
    __shared__ __align__(16) bf16 Bt[64 * 200];   // 25.6 KB, +8 pad breaks 32-bank stride
    __shared__ float gs[C_DIM], bs[C_DIM];
    const int K = C_DIM;
    int n0 = blockIdx.x * 64;
    int m0 = blockIdx.y * 64;
    int t = threadIdx.x;
    if (t < C_DIM) { gs[t] = gamma[t]; bs[t] = beta[t]; }
    if (blockIdx.x == 0 && blockIdx.y == 0 && t < 8) maxk2[t] = 0.0f;
    __syncthreads();

    int lane = t & 63, wave = t >> 6;
    {
        int pl = wave * 16 + (lane & 15);       // pixel within tile, 0..63
        int seg = lane >> 4;                    // 0..3 -> 48 channels each
        int p = n0 + pl;
        float v[48];
        float s = 0.f, ss = 0.f;
        for (int j = 0; j < 48; ++j) {
            float f = x[(seg * 48 + j) * N_PIX + p];
            v[j] = f; s += f; ss += f * f;
        }
        s += __shfl_xor(s, 16, 64); s += __shfl_xor(s, 32, 64);
        ss += __shfl_xor(ss, 16, 64); ss += __shfl_xor(ss, 32, 64);
        float mean = s * (1.0f / C_DIM);
        float var = ss * (1.0f / C_DIM) - mean * mean;
        float rstd = rsqrtf(var + 1e-5f);
        bf16* dst = Bt + pl * 200 + seg * 48;
        for (int g = 0; g < 6; ++g) {
            bf16x8 w;
            for (int j = 0; j < 8; ++j) {
                int c = seg * 48 + g * 8 + j;
                w[j] = (bf16)((v[g * 8 + j] - mean) * rstd * gs[c] + bs[c]);
            }
            *(bf16x8*)(dst + g * 8) = w;
        }
    }
    __syncthreads();

    int l16 = lane & 15, quad = lane >> 4;
    int wm = (wave >> 1) * 32, wn = (wave & 1) * 32;
    f32x4 acc[2][2] = {};
    for (int kk = 0; kk < K; kk += 32) {
        const f32x4* ar0 = (const f32x4*)(wqkv + (m0 + wm + l16) * K + kk + quad * 8);
        const f32x4* ar1 = (const f32x4*)(wqkv + (m0 + wm + 16 + l16) * K + kk + quad * 8);
        f32x4 w0a = ar0[0], w0b = ar0[1];
        f32x4 w1a = ar1[0], w1b = ar1[1];
        bf16x8 a0, a1;
        for (int j = 0; j < 4; ++j) {
            a0[j] = (bf16)w0a[j]; a0[4 + j] = (bf16)w0b[j];
            a1[j] = (bf16)w1a[j]; a1[4 + j] = (bf16)w1b[j];
        }
        bf16x8 b0 = *(const bf16x8*)(Bt + (wn + l16) * 200 + kk + quad * 8);
        bf16x8 b1 = *(const bf16x8*)(Bt + (wn + 16 + l16) * 200 + kk + quad * 8);
        acc[0][0] = mfma16(a0, b0, acc[0][0]);
        acc[0][1] = mfma16(a0, b1, acc[0][1]);
        acc[1][0] = mfma16(a1, b0, acc[1][0]);
        acc[1][1] = mfma16(a1, b1, acc[1][1]);
    }
    for (int i = 0; i < 2; ++i)
        for (int j = 0; j < 2; ++j)
            for (int r = 0; r < 4; ++r) {
                int row = m0 + wm + i * 16 + quad * 4 + r;
                int col = n0 + wn + j * 16 + l16;
                qkvb[(size_t)row * N_PIX + col] = (bf16)acc[i][j][r];
            }
}

// ---------------- depthwise 3x3 + bias, vectorized; q/k stores via LDS transpose ----------------
__global__ __launch_bounds__(256) void dwconv(const bf16* __restrict__ qkv,
                                              const float* __restrict__ wdw,
                                              const float* __restrict__ bdw,
                                              bf16* __restrict__ qt,
                                              bf16* __restrict__ kt,
                                              bf16* __restrict__ vl,
                                              float* __restrict__ maxk2) {
    __shared__ float k2s[24][64];
    __shared__ bf16 stg[64 * DPAD];   // [px][ch], 4 KB
    int bx = blockIdx.x;
    int part = bx >> 9;            // 512 blocks per part
    int h = (bx >> 6) & 7;
    int y = bx & 63;
    int t = threadIdx.x;
    int ch_local = t >> 3;         // 0..31 (24 active)
    int seg = t & 7;
    int px0 = seg * 8;
    bool active = ch_local < 24;

    float acc[8];
    if (active) {
        int ch = part * C_DIM + h * DHEAD + ch_local;
        const bf16* in = qkv + (size_t)ch * N_PIX;
        float w[9];
        for (int i = 0; i < 9; ++i) w[i] = wdw[ch * 9 + i];
        float bias = bdw[ch];
        float rowv[3][10];
        for (int r = 0; r < 3; ++r) {
            int yy = y + r - 1;
            if (yy >= 0 && yy < 64) {
                bf16x8 v8 = *(const bf16x8*)(in + yy * 64 + px0);
                for (int j = 0; j < 8; ++j) rowv[r][j + 1] = (float)v8[j];
                rowv[r][0] = (seg > 0) ? (float)in[yy * 64 + px0 - 1] : 0.f;
                rowv[r][9] = (seg < 7) ? (float)in[yy * 64 + px0 + 8] : 0.f;
            } else {
                for (int j = 0; j < 10; ++j) rowv[r][j] = 0.f;
            }
        }
        for (int j = 0; j < 8; ++j) {
            float a = bias;
            for (int r = 0; r < 3; ++r)
                a += w[r * 3 + 0] * rowv[r][j] + w[r * 3 + 1] * rowv[r][j + 1]
                   + w[r * 3 + 2] * rowv[r][j + 2];
            acc[j] = a;
        }
    }

    if (part == 2) {
        if (active) {
            bf16x8 v8;
            for (int j = 0; j < 8; ++j) v8[j] = (bf16)acc[j];
            *(bf16x8*)(vl + ((size_t)(h * DPAD + ch_local)) * N_PIX + y * 64 + px0) = v8;
        } else {
            int i = t - 192;           // pad rows 24..31 x 8 segments
            int dd = 24 + (i >> 3);
            int s2 = i & 7;
            bf16 val = (bf16)((dd == 24) ? 1.0f : 0.0f);
            bf16x8 v8;
            for (int j = 0; j < 8; ++j) v8[j] = val;
            *(bf16x8*)(vl + ((size_t)(h * DPAD + dd)) * N_PIX + y * 64 + s2 * 8) = v8;
        }
    } else {
        if (active) {
            for (int j = 0; j < 8; ++j)
                stg[(px0 + j) * DPAD + ch_local] = (bf16)acc[j];
        } else {
            int i = t - 192;           // px = i: zero pad ch 24..31
            bf16x8 z;
            for (int j = 0; j < 8; ++j) z[j] = (bf16)0.0f;
            *(bf16x8*)(stg + i * DPAD + 24) = z;
        }
        if (part == 1 && active)
            for (int j = 0; j < 8; ++j) k2s[ch_local][px0 + j] = acc[j] * acc[j];
        __syncthreads();
        bf16* dst = (part == 0 ? qt : kt) + ((size_t)h * N_PIX + y * 64) * DPAD;
        *(bf16x8*)(dst + t * 8) = *(const bf16x8*)(stg + t * 8);
        if (part == 1 && t < 64) {
            float s = 0.f;
            for (int c = 0; c < 24; ++c) s += k2s[c][t];
            for (int off = 1; off < 64; off <<= 1)
                s = fmaxf(s, __shfl_xor(s, off, 64));
            if (t == 0) atomicMax((unsigned int*)(maxk2 + h), __float_as_uint(s));
        }
    }
}

// ---------------- flash attention: all-register P (permuted-key PV), split-K=16, 8 blocks/CU ----------------
__global__ __launch_bounds__(256, 8) void flash_attn(const bf16* __restrict__ qt,
                                                     const bf16* __restrict__ kt,
                                                     const bf16* __restrict__ vl,
                                                     const float* __restrict__ temp,
                                                     const float* __restrict__ maxk2,
                                                     bf16* __restrict__ opart,
                                                     bf16* __restrict__ lpart) {
    int tid = threadIdx.x;
    int wave = tid >> 6, lane = tid & 63;
    int l16 = lane & 15, quad = lane >> 4;
    int head = blockIdx.x & 7;               // block -> XCD round-robin: head pinned per XCD
    int qb = (blockIdx.x >> 3) & 15;
    int split = blockIdx.x >> 7;             // 0..15
    int nbase = qb * 256 + wave * 64;
    float tl = temp[head] * 1.44269504f;

    const bf16* qrow = qt + ((size_t)head * N_PIX + nbase) * DPAD;
    bf16x8 aq[4];
    for (int f = 0; f < 4; ++f)
        aq[f] = *(const bf16x8*)(qrow + (size_t)(f * 16 + l16) * DPAD + quad * 8);

    float mk2 = maxk2[head];
    float Bb[4];
    for (int f = 0; f < 4; ++f) {
        float q2 = 0.f;
        for (int j = 0; j < 8; ++j) { float v = (float)aq[f][j]; q2 += v * v; }
        q2 += __shfl_xor(q2, 16, 64);
        q2 += __shfl_xor(q2, 32, 64);
        Bb[f] = fabsf(tl) * sqrtf(q2 * mk2) + 1.0f;
    }

    const bf16* kbase = kt + (size_t)head * N_PIX * DPAD;
    const bf16* vbase = vl + (size_t)head * DPAD * N_PIX;

    f32x4 o0[4] = {}, o1[4] = {};

    const int NITER = 64 / NSPLIT;           // 4
    int mbase = split * NITER * 64;

    // prologue: K fragments for iter 0
    bf16x8 ak[4];
    for (int mt = 0; mt < 4; ++mt)
        ak[mt] = *(const bf16x8*)(kbase + (size_t)(mbase + mt * 16 + l16) * DPAD + quad * 8);

    #pragma unroll 2
    for (int it = 0; it < NITER; ++it) {
        int m0 = mbase + it * 64;
        // V fragments, key-permuted to match QK output layout: slot group j<4 -> keys m+4q..,
        // j>=4 -> keys m+16+4q.. (kappa(8q+j) = 4q + (j&3) + 16*(j>>2), per 32-key half)
        const bf16* vr0 = vbase + (size_t)l16 * N_PIX + m0 + quad * 4;
        const bf16* vr1 = vbase + (size_t)(16 + l16) * N_PIX + m0 + quad * 4;
        bf16x4 v00 = *(const bf16x4*)(vr0);
        bf16x4 v01 = *(const bf16x4*)(vr0 + 16);
        bf16x4 v02 = *(const bf16x4*)(vr0 + 32);
        bf16x4 v03 = *(const bf16x4*)(vr0 + 48);
        bf16x4 v10 = *(const bf16x4*)(vr1);
        bf16x4 v11 = *(const bf16x4*)(vr1 + 16);
        bf16x4 v12 = *(const bf16x4*)(vr1 + 32);
        bf16x4 v13 = *(const bf16x4*)(vr1 + 48);
        bf16x8 av0, av1, av2, av3;
        for (int j = 0; j < 4; ++j) {
            av0[j] = v00[j]; av0[4 + j] = v01[j];
            av1[j] = v10[j]; av1[4 + j] = v11[j];
            av2[j] = v02[j]; av2[4 + j] = v03[j];
            av3[j] = v12[j]; av3[4 + j] = v13[j];
        }
        // prefetch next iter's K fragments (the latency-exposed loads)
        bf16x8 akn[4];
        if (it + 1 < NITER) {
            int m1 = m0 + 64;
            for (int mt = 0; mt < 4; ++mt)
                akn[mt] = *(const bf16x8*)(kbase + (size_t)(m1 + mt * 16 + l16) * DPAD + quad * 8);
        }

        for (int f = 0; f < 4; ++f) {
            f32x4 z = {0.f, 0.f, 0.f, 0.f};
            f32x4 st[4];
            for (int mt = 0; mt < 4; ++mt) st[mt] = mfma16(ak[mt], aq[f], z);
            // P stays in registers: lane(l16,quad) holds keys 16mt+4quad+r; with permuted V,
            // the PV B-operand is just {exp(st0),exp(st1)} / {exp(st2),exp(st3)}.
            bf16x8 ap0, ap1;
            for (int r = 0; r < 4; ++r) {
                ap0[r]     = (bf16)fast_exp2(__builtin_fmaf(st[0][r], tl, -Bb[f]));
                ap0[4 + r] = (bf16)fast_exp2(__builtin_fmaf(st[1][r], tl, -Bb[f]));
                ap1[r]     = (bf16)fast_exp2(__builtin_fmaf(st[2][r], tl, -Bb[f]));
                ap1[4 + r] = (bf16)fast_exp2(__builtin_fmaf(st[3][r], tl, -Bb[f]));
            }
            o0[f] = mfma16(av0, ap0, o0[f]);
            o1[f] = mfma16(av1, ap0, o1[f]);
            o0[f] = mfma16(av2, ap1, o0[f]);
            o1[f] = mfma16(av3, ap1, o1[f]);
        }
        if (it + 1 < NITER)
            for (int mt = 0; mt < 4; ++mt) ak[mt] = akn[mt];
    }

    for (int f = 0; f < 4; ++f) {
        int n = nbase + f * 16 + l16;
        size_t rowo = ((size_t)(split * 8 + head) * N_PIX + n) * 24;
        bf16x4 w0;
        for (int r = 0; r < 4; ++r) w0[r] = (bf16)o0[f][r];
        *(bf16x4*)(opart + rowo + quad * 4) = w0;
        if (quad < 2) {
            bf16x4 w1;
            for (int r = 0; r < 4; ++r) w1[r] = (bf16)o1[f][r];
            *(bf16x4*)(opart + rowo + 16 + quad * 4) = w1;
        }
        if (quad == 2)
            lpart[(size_t)(split * 8 + head) * N_PIX + n] = (bf16)o1[f][0];
    }
}

// ---------------- proj GEMM with fused split-K combine; wproj converted inline ----------------
__global__ __launch_bounds__(256) void gemm_proj(const float* __restrict__ wproj,
                                                 const bf16* __restrict__ opart,
                                                 const bf16* __restrict__ lpart,
                                                 float* __restrict__ outf,
                                                 const float* __restrict__ resid) {
    __shared__ __align__(16) bf16 Bld[32 * 200];
    const int K = C_DIM;
    int n0 = blockIdx.x * 32;
    int m0 = blockIdx.y * 64;
    int t = threadIdx.x;
    {
        int h = t >> 5, nl = t & 31;
        int n = n0 + nl;
        float acc[24];
        for (int j = 0; j < 24; ++j) acc[j] = 0.f;
        float l = 0.f;
        for (int s = 0; s < NSPLIT; ++s) {
            const bf16* row = opart + ((size_t)(s * 8 + h) * N_PIX + n) * 24;
            bf16x8 a = *(const bf16x8*)(row);
            bf16x8 b = *(const bf16x8*)(row + 8);
            bf16x8 c = *(const bf16x8*)(row + 16);
            for (int j = 0; j < 8; ++j) {
                acc[j] += (float)a[j];
                acc[8 + j] += (float)b[j];
                acc[16 + j] += (float)c[j];
            }
            l += (float)lpart[(size_t)(s * 8 + h) * N_PIX + n];
        }
        float inv = 1.0f / l;
        bf16* dst = Bld + nl * 200 + h * 24;
        for (int g = 0; g < 3; ++g) {
            bf16x8 w;
            for (int j = 0; j < 8; ++j) w[j] = (bf16)(acc[g * 8 + j] * inv);
            *(bf16x8*)(dst + g * 8) = w;
        }
    }
    __syncthreads();
    int wave = t >> 6, lane = t & 63;
    int l16 = lane & 15, quad = lane >> 4;
    int mrow = m0 + wave * 16;
    float rv[8];
    for (int j = 0; j < 2; ++j)
        for (int r = 0; r < 4; ++r)
            rv[j * 4 + r] = resid[(size_t)(mrow + quad * 4 + r) * N_PIX + n0 + j * 16 + l16];
    f32x4 acc2[2] = {};
    for (int kk = 0; kk < K; kk += 32) {
        const f32x4* ar = (const f32x4*)(wproj + (mrow + l16) * K + kk + quad * 8);
        f32x4 wa = ar[0], wb = ar[1];
        bf16x8 a;
        for (int j = 0; j < 4; ++j) { a[j] = (bf16)wa[j]; a[4 + j] = (bf16)wb[j]; }
        bf16x8 b0 = *(const bf16x8*)(Bld + l16 * 200 + kk + quad * 8);
        bf16x8 b1 = *(const bf16x8*)(Bld + (16 + l16) * 200 + kk + quad * 8);
        acc2[0] = mfma16(a, b0, acc2[0]);
        acc2[1] = mfma16(a, b1, acc2[1]);
    }
    for (int j = 0; j < 2; ++j)
        for (int r = 0; r < 4; ++r) {
            int row = mrow + quad * 4 + r;
            int col = n0 + j * 16 + l16;
            outf[(size_t)row * N_PIX + col] = acc2[j][r] + rv[j * 4 + r];
        }
}

extern "C" void kernel_launch(void* const* d_in, const int* in_sizes, int n_in,
                              void* d_out, int out_size, void* d_ws, size_t ws_size,
                              hipStream_t stream) {
    const float* x     = (const float*)d_in[0];
    const float* gamma = (const float*)d_in[1];
    const float* beta  = (const float*)d_in[2];
    const float* wqkv  = (const float*)d_in[3];
    const float* wdw   = (const float*)d_in[4];
    const float* bdw   = (const float*)d_in[5];
    const float* wproj = (const float*)d_in[6];
    const float* temp  = (const float*)d_in[7];
    float* out = (float*)d_out;

    char* ws = (char*)d_ws;
    bf16* qkv     = (bf16*)(ws + 0);          // 576*4096*2 = 4718592
    bf16* qt      = (bf16*)(ws + 4718592);    // 2097152
    bf16* kt      = (bf16*)(ws + 6815744);    // 2097152
    bf16* vl      = (bf16*)(ws + 8912896);    // 2097152
    bf16* opart   = (bf16*)(ws + 11010048);   // 16*8*4096*24*2 = 25165824
    bf16* lpart   = (bf16*)(ws + 36175872);   // 16*8*4096*2 = 1048576
    float* maxk2  = (float*)(ws + 37224448);  // 32

    ln_qkv<<<dim3(64, 9), 256, 0, stream>>>(x, gamma, beta, wqkv, qkv, maxk2);
    dwconv<<<1536, 256, 0, stream>>>(qkv, wdw, bdw, qt, kt, vl, maxk2);
    flash_attn<<<NSPLIT * 128, 256, 0, stream>>>(qt, kt, vl, temp, maxk2, opart, lpart);
    gemm_proj<<<dim3(128, 3), 256, 0, stream>>>(wproj, opart, lpart, out, x);
}

// Round 7
// 159.827 us; speedup vs baseline: 2.0126x; 2.0126x over previous
//
#include <hip/hip_runtime.h>
#include <hip/hip_bf16.h>

// MDTA: LN -> 1x1 conv (QKV) -> dw3x3 -> spatial attention (N=4096, d=24, 8 heads) -> proj + residual
// Round 18: undo the R17 register squeeze. launch_bounds(256,8) pinned flash to VGPR=32 ->
// total spill (1.1GB scratch traffic/dispatch, 220-260us at 62% HBM). Revert to (256,4)
// (R16's proven VGPR=64, zero spill; HW allows 8 waves/SIMD at 64 VGPR anyway) while KEEPING
// NSPLIT=16 (2048 blocks -> 8 blocks/CU resident; R16's occupancy was grid-limited at 1024).
// Single-variable A/B vs R16: same datapath, 2x resident waves.

typedef __bf16 bf16;
typedef __bf16 bf16x2 __attribute__((ext_vector_type(2)));
typedef __bf16 bf16x4 __attribute__((ext_vector_type(4)));
typedef __bf16 bf16x8 __attribute__((ext_vector_type(8)));
typedef float f32x4 __attribute__((ext_vector_type(4)));

#define C_DIM 192
#define N_PIX 4096
#define HEADS 8
#define DHEAD 24
#define DPAD 32
#define C3 576
#define NSPLIT 16

__device__ inline float fast_exp2(float x) {
#if __has_builtin(__builtin_amdgcn_exp2f)
    return __builtin_amdgcn_exp2f(x);
#else
    return exp2f(x);
#endif
}

__device__ inline f32x4 mfma16(bf16x8 a, bf16x8 b, f32x4 c) {
    return __builtin_amdgcn_mfma_f32_16x16x32_bf16(a, b, c, 0, 0, 0);
}

// ---------------- fused LN + QKV GEMM (64x64 tile): qkv[576,4096] = wqkv[576,192] * LN(x)[4096,192]^T ----------------
__global__ __launch_bounds__(256) void ln_qkv(const float* __restrict__ x,
                                              const float* __restrict__ gamma,
                                              const float* __restrict__ beta,
                                              const float* __restrict__ wqkv,
                                              bf16* __restrict__ qkvb,
                                              float* __restrict__ maxk2) {
    __shared__ __align__(16) bf16 Bt[64 * 200];   // 25.6 KB, +8 pad breaks 32-bank stride
    __shared__ float gs[C_DIM], bs[C_DIM];
    const int K = C_DIM;
    int n0 = blockIdx.x * 64;
    int m0 = blockIdx.y * 64;
    int t = threadIdx.x;
    if (t < C_DIM) { gs[t] = gamma[t]; bs[t] = beta[t]; }
    if (blockIdx.x == 0 && blockIdx.y == 0 && t < 8) maxk2[t] = 0.0f;
    __syncthreads();

    int lane = t & 63, wave = t >> 6;
    {
        int pl = wave * 16 + (lane & 15);       // pixel within tile, 0..63
        int seg = lane >> 4;                    // 0..3 -> 48 channels each
        int p = n0 + pl;
        float v[48];
        float s = 0.f, ss = 0.f;
        for (int j = 0; j < 48; ++j) {
            float f = x[(seg * 48 + j) * N_PIX + p];
            v[j] = f; s += f; ss += f * f;
        }
        s += __shfl_xor(s, 16, 64); s += __shfl_xor(s, 32, 64);
        ss += __shfl_xor(ss, 16, 64); ss += __shfl_xor(ss, 32, 64);
        float mean = s * (1.0f / C_DIM);
        float var = ss * (1.0f / C_DIM) - mean * mean;
        float rstd = rsqrtf(var + 1e-5f);
        bf16* dst = Bt + pl * 200 + seg * 48;
        for (int g = 0; g < 6; ++g) {
            bf16x8 w;
            for (int j = 0; j < 8; ++j) {
                int c = seg * 48 + g * 8 + j;
                w[j] = (bf16)((v[g * 8 + j] - mean) * rstd * gs[c] + bs[c]);
            }
            *(bf16x8*)(dst + g * 8) = w;
        }
    }
    __syncthreads();

    int l16 = lane & 15, quad = lane >> 4;
    int wm = (wave >> 1) * 32, wn = (wave & 1) * 32;
    f32x4 acc[2][2] = {};
    for (int kk = 0; kk < K; kk += 32) {
        const f32x4* ar0 = (const f32x4*)(wqkv + (m0 + wm + l16) * K + kk + quad * 8);
        const f32x4* ar1 = (const f32x4*)(wqkv + (m0 + wm + 16 + l16) * K + kk + quad * 8);
        f32x4 w0a = ar0[0], w0b = ar0[1];
        f32x4 w1a = ar1[0], w1b = ar1[1];
        bf16x8 a0, a1;
        for (int j = 0; j < 4; ++j) {
            a0[j] = (bf16)w0a[j]; a0[4 + j] = (bf16)w0b[j];
            a1[j] = (bf16)w1a[j]; a1[4 + j] = (bf16)w1b[j];
        }
        bf16x8 b0 = *(const bf16x8*)(Bt + (wn + l16) * 200 + kk + quad * 8);
        bf16x8 b1 = *(const bf16x8*)(Bt + (wn + 16 + l16) * 200 + kk + quad * 8);
        acc[0][0] = mfma16(a0, b0, acc[0][0]);
        acc[0][1] = mfma16(a0, b1, acc[0][1]);
        acc[1][0] = mfma16(a1, b0, acc[1][0]);
        acc[1][1] = mfma16(a1, b1, acc[1][1]);
    }
    for (int i = 0; i < 2; ++i)
        for (int j = 0; j < 2; ++j)
            for (int r = 0; r < 4; ++r) {
                int row = m0 + wm + i * 16 + quad * 4 + r;
                int col = n0 + wn + j * 16 + l16;
                qkvb[(size_t)row * N_PIX + col] = (bf16)acc[i][j][r];
            }
}

// ---------------- depthwise 3x3 + bias, vectorized; q/k stores via LDS transpose ----------------
__global__ __launch_bounds__(256) void dwconv(const bf16* __restrict__ qkv,
                                              const float* __restrict__ wdw,
                                              const float* __restrict__ bdw,
                                              bf16* __restrict__ qt,
                                              bf16* __restrict__ kt,
                                              bf16* __restrict__ vl,
                                              float* __restrict__ maxk2) {
    __shared__ float k2s[24][64];
    __shared__ bf16 stg[64 * DPAD];   // [px][ch], 4 KB
    int bx = blockIdx.x;
    int part = bx >> 9;            // 512 blocks per part
    int h = (bx >> 6) & 7;
    int y = bx & 63;
    int t = threadIdx.x;
    int ch_local = t >> 3;         // 0..31 (24 active)
    int seg = t & 7;
    int px0 = seg * 8;
    bool active = ch_local < 24;

    float acc[8];
    if (active) {
        int ch = part * C_DIM + h * DHEAD + ch_local;
        const bf16* in = qkv + (size_t)ch * N_PIX;
        float w[9];
        for (int i = 0; i < 9; ++i) w[i] = wdw[ch * 9 + i];
        float bias = bdw[ch];
        float rowv[3][10];
        for (int r = 0; r < 3; ++r) {
            int yy = y + r - 1;
            if (yy >= 0 && yy < 64) {
                bf16x8 v8 = *(const bf16x8*)(in + yy * 64 + px0);
                for (int j = 0; j < 8; ++j) rowv[r][j + 1] = (float)v8[j];
                rowv[r][0] = (seg > 0) ? (float)in[yy * 64 + px0 - 1] : 0.f;
                rowv[r][9] = (seg < 7) ? (float)in[yy * 64 + px0 + 8] : 0.f;
            } else {
                for (int j = 0; j < 10; ++j) rowv[r][j] = 0.f;
            }
        }
        for (int j = 0; j < 8; ++j) {
            float a = bias;
            for (int r = 0; r < 3; ++r)
                a += w[r * 3 + 0] * rowv[r][j] + w[r * 3 + 1] * rowv[r][j + 1]
                   + w[r * 3 + 2] * rowv[r][j + 2];
            acc[j] = a;
        }
    }

    if (part == 2) {
        if (active) {
            bf16x8 v8;
            for (int j = 0; j < 8; ++j) v8[j] = (bf16)acc[j];
            *(bf16x8*)(vl + ((size_t)(h * DPAD + ch_local)) * N_PIX + y * 64 + px0) = v8;
        } else {
            int i = t - 192;           // pad rows 24..31 x 8 segments
            int dd = 24 + (i >> 3);
            int s2 = i & 7;
            bf16 val = (bf16)((dd == 24) ? 1.0f : 0.0f);
            bf16x8 v8;
            for (int j = 0; j < 8; ++j) v8[j] = val;
            *(bf16x8*)(vl + ((size_t)(h * DPAD + dd)) * N_PIX + y * 64 + s2 * 8) = v8;
        }
    } else {
        if (active) {
            for (int j = 0; j < 8; ++j)
                stg[(px0 + j) * DPAD + ch_local] = (bf16)acc[j];
        } else {
            int i = t - 192;           // px = i: zero pad ch 24..31
            bf16x8 z;
            for (int j = 0; j < 8; ++j) z[j] = (bf16)0.0f;
            *(bf16x8*)(stg + i * DPAD + 24) = z;
        }
        if (part == 1 && active)
            for (int j = 0; j < 8; ++j) k2s[ch_local][px0 + j] = acc[j] * acc[j];
        __syncthreads();
        bf16* dst = (part == 0 ? qt : kt) + ((size_t)h * N_PIX + y * 64) * DPAD;
        *(bf16x8*)(dst + t * 8) = *(const bf16x8*)(stg + t * 8);
        if (part == 1 && t < 64) {
            float s = 0.f;
            for (int c = 0; c < 24; ++c) s += k2s[c][t];
            for (int off = 1; off < 64; off <<= 1)
                s = fmaxf(s, __shfl_xor(s, off, 64));
            if (t == 0) atomicMax((unsigned int*)(maxk2 + h), __float_as_uint(s));
        }
    }
}

// ---------------- flash attention: all-register P (permuted-key PV), split-K=16 ----------------
__global__ __launch_bounds__(256, 4) void flash_attn(const bf16* __restrict__ qt,
                                                     const bf16* __restrict__ kt,
                                                     const bf16* __restrict__ vl,
                                                     const float* __restrict__ temp,
                                                     const float* __restrict__ maxk2,
                                                     bf16* __restrict__ opart,
                                                     bf16* __restrict__ lpart) {
    int tid = threadIdx.x;
    int wave = tid >> 6, lane = tid & 63;
    int l16 = lane & 15, quad = lane >> 4;
    int head = blockIdx.x & 7;               // block -> XCD round-robin: head pinned per XCD
    int qb = (blockIdx.x >> 3) & 15;
    int split = blockIdx.x >> 7;             // 0..15
    int nbase = qb * 256 + wave * 64;
    float tl = temp[head] * 1.44269504f;

    const bf16* qrow = qt + ((size_t)head * N_PIX + nbase) * DPAD;
    bf16x8 aq[4];
    for (int f = 0; f < 4; ++f)
        aq[f] = *(const bf16x8*)(qrow + (size_t)(f * 16 + l16) * DPAD + quad * 8);

    float mk2 = maxk2[head];
    float Bb[4];
    for (int f = 0; f < 4; ++f) {
        float q2 = 0.f;
        for (int j = 0; j < 8; ++j) { float v = (float)aq[f][j]; q2 += v * v; }
        q2 += __shfl_xor(q2, 16, 64);
        q2 += __shfl_xor(q2, 32, 64);
        Bb[f] = fabsf(tl) * sqrtf(q2 * mk2) + 1.0f;
    }

    const bf16* kbase = kt + (size_t)head * N_PIX * DPAD;
    const bf16* vbase = vl + (size_t)head * DPAD * N_PIX;

    f32x4 o0[4] = {}, o1[4] = {};

    const int NITER = 64 / NSPLIT;           // 4
    int mbase = split * NITER * 64;

    // prologue: K fragments for iter 0
    bf16x8 ak[4];
    for (int mt = 0; mt < 4; ++mt)
        ak[mt] = *(const bf16x8*)(kbase + (size_t)(mbase + mt * 16 + l16) * DPAD + quad * 8);

    #pragma unroll 2
    for (int it = 0; it < NITER; ++it) {
        int m0 = mbase + it * 64;
        // V fragments, key-permuted to match QK output layout: slot group j<4 -> keys m+4q..,
        // j>=4 -> keys m+16+4q.. (kappa(8q+j) = 4q + (j&3) + 16*(j>>2), per 32-key half)
        const bf16* vr0 = vbase + (size_t)l16 * N_PIX + m0 + quad * 4;
        const bf16* vr1 = vbase + (size_t)(16 + l16) * N_PIX + m0 + quad * 4;
        bf16x4 v00 = *(const bf16x4*)(vr0);
        bf16x4 v01 = *(const bf16x4*)(vr0 + 16);
        bf16x4 v02 = *(const bf16x4*)(vr0 + 32);
        bf16x4 v03 = *(const bf16x4*)(vr0 + 48);
        bf16x4 v10 = *(const bf16x4*)(vr1);
        bf16x4 v11 = *(const bf16x4*)(vr1 + 16);
        bf16x4 v12 = *(const bf16x4*)(vr1 + 32);
        bf16x4 v13 = *(const bf16x4*)(vr1 + 48);
        bf16x8 av0, av1, av2, av3;
        for (int j = 0; j < 4; ++j) {
            av0[j] = v00[j]; av0[4 + j] = v01[j];
            av1[j] = v10[j]; av1[4 + j] = v11[j];
            av2[j] = v02[j]; av2[4 + j] = v03[j];
            av3[j] = v12[j]; av3[4 + j] = v13[j];
        }
        // prefetch next iter's K fragments (the latency-exposed loads)
        bf16x8 akn[4];
        if (it + 1 < NITER) {
            int m1 = m0 + 64;
            for (int mt = 0; mt < 4; ++mt)
                akn[mt] = *(const bf16x8*)(kbase + (size_t)(m1 + mt * 16 + l16) * DPAD + quad * 8);
        }

        for (int f = 0; f < 4; ++f) {
            f32x4 z = {0.f, 0.f, 0.f, 0.f};
            f32x4 st[4];
            for (int mt = 0; mt < 4; ++mt) st[mt] = mfma16(ak[mt], aq[f], z);
            // P stays in registers: lane(l16,quad) holds keys 16mt+4quad+r; with permuted V,
            // the PV B-operand is just {exp(st0),exp(st1)} / {exp(st2),exp(st3)}.
            bf16x8 ap0, ap1;
            for (int r = 0; r < 4; ++r) {
                ap0[r]     = (bf16)fast_exp2(__builtin_fmaf(st[0][r], tl, -Bb[f]));
                ap0[4 + r] = (bf16)fast_exp2(__builtin_fmaf(st[1][r], tl, -Bb[f]));
                ap1[r]     = (bf16)fast_exp2(__builtin_fmaf(st[2][r], tl, -Bb[f]));
                ap1[4 + r] = (bf16)fast_exp2(__builtin_fmaf(st[3][r], tl, -Bb[f]));
            }
            o0[f] = mfma16(av0, ap0, o0[f]);
            o1[f] = mfma16(av1, ap0, o1[f]);
            o0[f] = mfma16(av2, ap1, o0[f]);
            o1[f] = mfma16(av3, ap1, o1[f]);
        }
        if (it + 1 < NITER)
            for (int mt = 0; mt < 4; ++mt) ak[mt] = akn[mt];
    }

    for (int f = 0; f < 4; ++f) {
        int n = nbase + f * 16 + l16;
        size_t rowo = ((size_t)(split * 8 + head) * N_PIX + n) * 24;
        bf16x4 w0;
        for (int r = 0; r < 4; ++r) w0[r] = (bf16)o0[f][r];
        *(bf16x4*)(opart + rowo + quad * 4) = w0;
        if (quad < 2) {
            bf16x4 w1;
            for (int r = 0; r < 4; ++r) w1[r] = (bf16)o1[f][r];
            *(bf16x4*)(opart + rowo + 16 + quad * 4) = w1;
        }
        if (quad == 2)
            lpart[(size_t)(split * 8 + head) * N_PIX + n] = (bf16)o1[f][0];
    }
}

// ---------------- proj GEMM with fused split-K combine; wproj converted inline ----------------
__global__ __launch_bounds__(256) void gemm_proj(const float* __restrict__ wproj,
                                                 const bf16* __restrict__ opart,
                                                 const bf16* __restrict__ lpart,
                                                 float* __restrict__ outf,
                                                 const float* __restrict__ resid) {
    __shared__ __align__(16) bf16 Bld[32 * 200];
    const int K = C_DIM;
    int n0 = blockIdx.x * 32;
    int m0 = blockIdx.y * 64;
    int t = threadIdx.x;
    {
        int h = t >> 5, nl = t & 31;
        int n = n0 + nl;
        float acc[24];
        for (int j = 0; j < 24; ++j) acc[j] = 0.f;
        float l = 0.f;
        for (int s = 0; s < NSPLIT; ++s) {
            const bf16* row = opart + ((size_t)(s * 8 + h) * N_PIX + n) * 24;
            bf16x8 a = *(const bf16x8*)(row);
            bf16x8 b = *(const bf16x8*)(row + 8);
            bf16x8 c = *(const bf16x8*)(row + 16);
            for (int j = 0; j < 8; ++j) {
                acc[j] += (float)a[j];
                acc[8 + j] += (float)b[j];
                acc[16 + j] += (float)c[j];
            }
            l += (float)lpart[(size_t)(s * 8 + h) * N_PIX + n];
        }
        float inv = 1.0f / l;
        bf16* dst = Bld + nl * 200 + h * 24;
        for (int g = 0; g < 3; ++g) {
            bf16x8 w;
            for (int j = 0; j < 8; ++j) w[j] = (bf16)(acc[g * 8 + j] * inv);
            *(bf16x8*)(dst + g * 8) = w;
        }
    }
    __syncthreads();
    int wave = t >> 6, lane = t & 63;
    int l16 = lane & 15, quad = lane >> 4;
    int mrow = m0 + wave * 16;
    float rv[8];
    for (int j = 0; j < 2; ++j)
        for (int r = 0; r < 4; ++r)
            rv[j * 4 + r] = resid[(size_t)(mrow + quad * 4 + r) * N_PIX + n0 + j * 16 + l16];
    f32x4 acc2[2] = {};
    for (int kk = 0; kk < K; kk += 32) {
        const f32x4* ar = (const f32x4*)(wproj + (mrow + l16) * K + kk + quad * 8);
        f32x4 wa = ar[0], wb = ar[1];
        bf16x8 a;
        for (int j = 0; j < 4; ++j) { a[j] = (bf16)wa[j]; a[4 + j] = (bf16)wb[j]; }
        bf16x8 b0 = *(const bf16x8*)(Bld + l16 * 200 + kk + quad * 8);
        bf16x8 b1 = *(const bf16x8*)(Bld + (16 + l16) * 200 + kk + quad * 8);
        acc2[0] = mfma16(a, b0, acc2[0]);
        acc2[1] = mfma16(a, b1, acc2[1]);
    }
    for (int j = 0; j < 2; ++j)
        for (int r = 0; r < 4; ++r) {
            int row = mrow + quad * 4 + r;
            int col = n0 + j * 16 + l16;
            outf[(size_t)row * N_PIX + col] = acc2[j][r] + rv[j * 4 + r];
        }
}

extern "C" void kernel_launch(void* const* d_in, const int* in_sizes, int n_in,
                              void* d_out, int out_size, void* d_ws, size_t ws_size,
                              hipStream_t stream) {
    const float* x     = (const float*)d_in[0];
    const float* gamma = (const float*)d_in[1];
    const float* beta  = (const float*)d_in[2];
    const float* wqkv  = (const float*)d_in[3];
    const float* wdw   = (const float*)d_in[4];
    const float* bdw   = (const float*)d_in[5];
    const float* wproj = (const float*)d_in[6];
    const float* temp  = (const float*)d_in[7];
    float* out = (float*)d_out;

    char* ws = (char*)d_ws;
    bf16* qkv     = (bf16*)(ws + 0);          // 576*4096*2 = 4718592
    bf16* qt      = (bf16*)(ws + 4718592);    // 2097152
    bf16* kt      = (bf16*)(ws + 6815744);    // 2097152
    bf16* vl      = (bf16*)(ws + 8912896);    // 2097152
    bf16* opart   = (bf16*)(ws + 11010048);   // 16*8*4096*24*2 = 25165824
    bf16* lpart   = (bf16*)(ws + 36175872);   // 16*8*4096*2 = 1048576
    float* maxk2  = (float*)(ws + 37224448);  // 32

    ln_qkv<<<dim3(64, 9), 256, 0, stream>>>(x, gamma, beta, wqkv, qkv, maxk2);
    dwconv<<<1536, 256, 0, stream>>>(qkv, wdw, bdw, qt, kt, vl, maxk2);
    flash_attn<<<NSPLIT * 128, 256, 0, stream>>>(qt, kt, vl, temp, maxk2, opart, lpart);
    gemm_proj<<<dim3(128, 3), 256, 0, stream>>>(wproj, opart, lpart, out, x);
}

// Round 8
// 131.173 us; speedup vs baseline: 2.4522x; 1.2184x over previous
//
#include <hip/hip_runtime.h>
#include <hip/hip_bf16.h>

// MDTA: LN -> 1x1 conv (QKV) -> dw3x3 -> spatial attention (N=4096, d=24, 8 heads) -> proj + residual
// Round 19: restore the best verified build (R15/131.6us: LDS-P flash w/ per-fragment buffers,
// NSPLIT=8) and add s_setprio(1) around each fragment's MFMA/exp/PV cluster (T5: +4-7% on attn
// with independent out-of-phase blocks; this kernel has no barriers, 4 indep blocks/CU).
// Evidence ledger: register-P flash = +12us (R16: repack VALU + 16-deep cvt chain feeds MFMA);
// NSPLIT=16 = +28us (R18: residency hard-capped 4 blocks/CU by unified VGPR+AGPR ~128/thread,
// and 25MB opart thrashes the 4MB/XCD L2 at 3.1MB/slice). Harness floor: ~84us of dur_us is
// two 256MB workspace-poison fills; controllable pipeline ~47us (flash ~33, others ~14).

typedef __bf16 bf16;
typedef __bf16 bf16x2 __attribute__((ext_vector_type(2)));
typedef __bf16 bf16x4 __attribute__((ext_vector_type(4)));
typedef __bf16 bf16x8 __attribute__((ext_vector_type(8)));
typedef float f32x4 __attribute__((ext_vector_type(4)));

#define C_DIM 192
#define N_PIX 4096
#define HEADS 8
#define DHEAD 24
#define DPAD 32
#define C3 576
#define NSPLIT 8

__device__ inline float fast_exp2(float x) {
#if __has_builtin(__builtin_amdgcn_exp2f)
    return __builtin_amdgcn_exp2f(x);
#else
    return exp2f(x);
#endif
}

__device__ inline f32x4 mfma16(bf16x8 a, bf16x8 b, f32x4 c) {
    return __builtin_amdgcn_mfma_f32_16x16x32_bf16(a, b, c, 0, 0, 0);
}

// ---------------- fused LN + QKV GEMM (64x64 tile): qkv[576,4096] = wqkv[576,192] * LN(x)[4096,192]^T ----------------
__global__ __launch_bounds__(256) void ln_qkv(const float* __restrict__ x,
                                              const float* __restrict__ gamma,
                                              const float* __restrict__ beta,
                                              const float* __restrict__ wqkv,
                                              bf16* __restrict__ qkvb,
                                              float* __restrict__ maxk2) {
    __shared__ __align__(16) bf16 Bt[64 * 200];   // 25.6 KB, +8 pad breaks 32-bank stride
    __shared__ float gs[C_DIM], bs[C_DIM];
    const int K = C_DIM;
    int n0 = blockIdx.x * 64;
    int m0 = blockIdx.y * 64;
    int t = threadIdx.x;
    if (t < C_DIM) { gs[t] = gamma[t]; bs[t] = beta[t]; }
    if (blockIdx.x == 0 && blockIdx.y == 0 && t < 8) maxk2[t] = 0.0f;
    __syncthreads();

    int lane = t & 63, wave = t >> 6;
    {
        int pl = wave * 16 + (lane & 15);       // pixel within tile, 0..63
        int seg = lane >> 4;                    // 0..3 -> 48 channels each
        int p = n0 + pl;
        float v[48];
        float s = 0.f, ss = 0.f;
        for (int j = 0; j < 48; ++j) {
            float f = x[(seg * 48 + j) * N_PIX + p];
            v[j] = f; s += f; ss += f * f;
        }
        s += __shfl_xor(s, 16, 64); s += __shfl_xor(s, 32, 64);
        ss += __shfl_xor(ss, 16, 64); ss += __shfl_xor(ss, 32, 64);
        float mean = s * (1.0f / C_DIM);
        float var = ss * (1.0f / C_DIM) - mean * mean;
        float rstd = rsqrtf(var + 1e-5f);
        bf16* dst = Bt + pl * 200 + seg * 48;
        for (int g = 0; g < 6; ++g) {
            bf16x8 w;
            for (int j = 0; j < 8; ++j) {
                int c = seg * 48 + g * 8 + j;
                w[j] = (bf16)((v[g * 8 + j] - mean) * rstd * gs[c] + bs[c]);
            }
            *(bf16x8*)(dst + g * 8) = w;
        }
    }
    __syncthreads();

    int l16 = lane & 15, quad = lane >> 4;
    int wm = (wave >> 1) * 32, wn = (wave & 1) * 32;
    f32x4 acc[2][2] = {};
    for (int kk = 0; kk < K; kk += 32) {
        const f32x4* ar0 = (const f32x4*)(wqkv + (m0 + wm + l16) * K + kk + quad * 8);
        const f32x4* ar1 = (const f32x4*)(wqkv + (m0 + wm + 16 + l16) * K + kk + quad * 8);
        f32x4 w0a = ar0[0], w0b = ar0[1];
        f32x4 w1a = ar1[0], w1b = ar1[1];
        bf16x8 a0, a1;
        for (int j = 0; j < 4; ++j) {
            a0[j] = (bf16)w0a[j]; a0[4 + j] = (bf16)w0b[j];
            a1[j] = (bf16)w1a[j]; a1[4 + j] = (bf16)w1b[j];
        }
        bf16x8 b0 = *(const bf16x8*)(Bt + (wn + l16) * 200 + kk + quad * 8);
        bf16x8 b1 = *(const bf16x8*)(Bt + (wn + 16 + l16) * 200 + kk + quad * 8);
        acc[0][0] = mfma16(a0, b0, acc[0][0]);
        acc[0][1] = mfma16(a0, b1, acc[0][1]);
        acc[1][0] = mfma16(a1, b0, acc[1][0]);
        acc[1][1] = mfma16(a1, b1, acc[1][1]);
    }
    for (int i = 0; i < 2; ++i)
        for (int j = 0; j < 2; ++j)
            for (int r = 0; r < 4; ++r) {
                int row = m0 + wm + i * 16 + quad * 4 + r;
                int col = n0 + wn + j * 16 + l16;
                qkvb[(size_t)row * N_PIX + col] = (bf16)acc[i][j][r];
            }
}

// ---------------- depthwise 3x3 + bias, vectorized; q/k stores via LDS transpose ----------------
__global__ __launch_bounds__(256) void dwconv(const bf16* __restrict__ qkv,
                                              const float* __restrict__ wdw,
                                              const float* __restrict__ bdw,
                                              bf16* __restrict__ qt,
                                              bf16* __restrict__ kt,
                                              bf16* __restrict__ vl,
                                              float* __restrict__ maxk2) {
    __shared__ float k2s[24][64];
    __shared__ bf16 stg[64 * DPAD];   // [px][ch], 4 KB
    int bx = blockIdx.x;
    int part = bx >> 9;            // 512 blocks per part
    int h = (bx >> 6) & 7;
    int y = bx & 63;
    int t = threadIdx.x;
    int ch_local = t >> 3;         // 0..31 (24 active)
    int seg = t & 7;
    int px0 = seg * 8;
    bool active = ch_local < 24;

    float acc[8];
    if (active) {
        int ch = part * C_DIM + h * DHEAD + ch_local;
        const bf16* in = qkv + (size_t)ch * N_PIX;
        float w[9];
        for (int i = 0; i < 9; ++i) w[i] = wdw[ch * 9 + i];
        float bias = bdw[ch];
        float rowv[3][10];
        for (int r = 0; r < 3; ++r) {
            int yy = y + r - 1;
            if (yy >= 0 && yy < 64) {
                bf16x8 v8 = *(const bf16x8*)(in + yy * 64 + px0);
                for (int j = 0; j < 8; ++j) rowv[r][j + 1] = (float)v8[j];
                rowv[r][0] = (seg > 0) ? (float)in[yy * 64 + px0 - 1] : 0.f;
                rowv[r][9] = (seg < 7) ? (float)in[yy * 64 + px0 + 8] : 0.f;
            } else {
                for (int j = 0; j < 10; ++j) rowv[r][j] = 0.f;
            }
        }
        for (int j = 0; j < 8; ++j) {
            float a = bias;
            for (int r = 0; r < 3; ++r)
                a += w[r * 3 + 0] * rowv[r][j] + w[r * 3 + 1] * rowv[r][j + 1]
                   + w[r * 3 + 2] * rowv[r][j + 2];
            acc[j] = a;
        }
    }

    if (part == 2) {
        if (active) {
            bf16x8 v8;
            for (int j = 0; j < 8; ++j) v8[j] = (bf16)acc[j];
            *(bf16x8*)(vl + ((size_t)(h * DPAD + ch_local)) * N_PIX + y * 64 + px0) = v8;
        } else {
            int i = t - 192;           // pad rows 24..31 x 8 segments
            int dd = 24 + (i >> 3);
            int s2 = i & 7;
            bf16 val = (bf16)((dd == 24) ? 1.0f : 0.0f);
            bf16x8 v8;
            for (int j = 0; j < 8; ++j) v8[j] = val;
            *(bf16x8*)(vl + ((size_t)(h * DPAD + dd)) * N_PIX + y * 64 + s2 * 8) = v8;
        }
    } else {
        if (active) {
            for (int j = 0; j < 8; ++j)
                stg[(px0 + j) * DPAD + ch_local] = (bf16)acc[j];
        } else {
            int i = t - 192;           // px = i: zero pad ch 24..31
            bf16x8 z;
            for (int j = 0; j < 8; ++j) z[j] = (bf16)0.0f;
            *(bf16x8*)(stg + i * DPAD + 24) = z;
        }
        if (part == 1 && active)
            for (int j = 0; j < 8; ++j) k2s[ch_local][px0 + j] = acc[j] * acc[j];
        __syncthreads();
        bf16* dst = (part == 0 ? qt : kt) + ((size_t)h * N_PIX + y * 64) * DPAD;
        *(bf16x8*)(dst + t * 8) = *(const bf16x8*)(stg + t * 8);
        if (part == 1 && t < 64) {
            float s = 0.f;
            for (int c = 0; c < 24; ++c) s += k2s[c][t];
            for (int off = 1; off < 64; off <<= 1)
                s = fmaxf(s, __shfl_xor(s, off, 64));
            if (t == 0) atomicMax((unsigned int*)(maxk2 + h), __float_as_uint(s));
        }
    }
}

// ---------------- flash attention: per-fragment LDS P buffers, K-prefetch pipeline, setprio core ----------------
__global__ __launch_bounds__(256, 4) void flash_attn(const bf16* __restrict__ qt,
                                                     const bf16* __restrict__ kt,
                                                     const bf16* __restrict__ vl,
                                                     const float* __restrict__ temp,
                                                     const float* __restrict__ maxk2,
                                                     bf16* __restrict__ opart,
                                                     bf16* __restrict__ lpart) {
    __shared__ __align__(16) bf16 Plds[16 * 1024];  // 8KB/wave: 4 fragments x 2KB each (no aliasing)

    int tid = threadIdx.x;
    int wave = tid >> 6, lane = tid & 63;
    int l16 = lane & 15, quad = lane >> 4;
    int head = blockIdx.x & 7;               // block -> XCD round-robin: head pinned per XCD
    int qb = (blockIdx.x >> 3) & 15;
    int split = blockIdx.x >> 7;             // 0..7
    int nbase = qb * 256 + wave * 64;
    float tl = temp[head] * 1.44269504f;

    const bf16* qrow = qt + ((size_t)head * N_PIX + nbase) * DPAD;
    bf16x8 aq[4];
    for (int f = 0; f < 4; ++f)
        aq[f] = *(const bf16x8*)(qrow + (size_t)(f * 16 + l16) * DPAD + quad * 8);

    float mk2 = maxk2[head];
    float Bb[4];
    for (int f = 0; f < 4; ++f) {
        float q2 = 0.f;
        for (int j = 0; j < 8; ++j) { float v = (float)aq[f][j]; q2 += v * v; }
        q2 += __shfl_xor(q2, 16, 64);
        q2 += __shfl_xor(q2, 32, 64);
        Bb[f] = fabsf(tl) * sqrtf(q2 * mk2) + 1.0f;
    }

    const bf16* kbase = kt + (size_t)head * N_PIX * DPAD;
    const bf16* vbase = vl + (size_t)head * DPAD * N_PIX;
    bf16* pw = Plds + wave * 4096;           // 4 x 1024 per wave

    f32x4 o0[4] = {}, o1[4] = {};

    const int NITER = 64 / NSPLIT;           // 8
    int mbase = split * NITER * 64;

    // prologue: K fragments for iter 0
    bf16x8 ak[4];
    for (int mt = 0; mt < 4; ++mt)
        ak[mt] = *(const bf16x8*)(kbase + (size_t)(mbase + mt * 16 + l16) * DPAD + quad * 8);

    #pragma unroll 2
    for (int it = 0; it < NITER; ++it) {
        int m0 = mbase + it * 64;
        // V fragments for this iter (consumed late -> latency self-hiding)
        bf16x8 av0 = *(const bf16x8*)(vbase + (size_t)l16 * N_PIX + m0 + quad * 8);
        bf16x8 av1 = *(const bf16x8*)(vbase + (size_t)(16 + l16) * N_PIX + m0 + quad * 8);
        bf16x8 av2 = *(const bf16x8*)(vbase + (size_t)l16 * N_PIX + m0 + 32 + quad * 8);
        bf16x8 av3 = *(const bf16x8*)(vbase + (size_t)(16 + l16) * N_PIX + m0 + 32 + quad * 8);
        // prefetch next iter's K fragments (the latency-exposed loads)
        bf16x8 akn[4];
        if (it + 1 < NITER) {
            int m1 = m0 + 64;
            for (int mt = 0; mt < 4; ++mt)
                akn[mt] = *(const bf16x8*)(kbase + (size_t)(m1 + mt * 16 + l16) * DPAD + quad * 8);
        }

        for (int f = 0; f < 4; ++f) {
            bf16* pwf = pw + f * 1024;       // private region per fragment -> no false DS deps
            __builtin_amdgcn_s_setprio(1);
            f32x4 z = {0.f, 0.f, 0.f, 0.f};
            f32x4 st[4];
            for (int mt = 0; mt < 4; ++mt) st[mt] = mfma16(ak[mt], aq[f], z);
            for (int mt = 0; mt < 4; ++mt) {
                bf16x4 pk;
                for (int r = 0; r < 4; ++r)
                    pk[r] = (bf16)fast_exp2(__builtin_fmaf(st[mt][r], tl, -Bb[f]));
                int chunk = mt * 2 + (quad >> 1);
                *(bf16x4*)(pwf + (chunk * 16 + l16) * 8 + (quad & 1) * 4) = pk;
            }
            bf16x8 ap0 = *(const bf16x8*)(pwf + (quad * 16 + l16) * 8);
            bf16x8 ap1 = *(const bf16x8*)(pwf + ((4 + quad) * 16 + l16) * 8);
            o0[f] = mfma16(av0, ap0, o0[f]);
            o1[f] = mfma16(av1, ap0, o1[f]);
            o0[f] = mfma16(av2, ap1, o0[f]);
            o1[f] = mfma16(av3, ap1, o1[f]);
            __builtin_amdgcn_s_setprio(0);
        }
        if (it + 1 < NITER)
            for (int mt = 0; mt < 4; ++mt) ak[mt] = akn[mt];
    }

    for (int f = 0; f < 4; ++f) {
        int n = nbase + f * 16 + l16;
        size_t rowo = ((size_t)(split * 8 + head) * N_PIX + n) * 24;
        bf16x4 w0;
        for (int r = 0; r < 4; ++r) w0[r] = (bf16)o0[f][r];
        *(bf16x4*)(opart + rowo + quad * 4) = w0;
        if (quad < 2) {
            bf16x4 w1;
            for (int r = 0; r < 4; ++r) w1[r] = (bf16)o1[f][r];
            *(bf16x4*)(opart + rowo + 16 + quad * 4) = w1;
        }
        if (quad == 2)
            lpart[(size_t)(split * 8 + head) * N_PIX + n] = (bf16)o1[f][0];
    }
}

// ---------------- proj GEMM with fused split-K combine; wproj converted inline ----------------
__global__ __launch_bounds__(256) void gemm_proj(const float* __restrict__ wproj,
                                                 const bf16* __restrict__ opart,
                                                 const bf16* __restrict__ lpart,
                                                 float* __restrict__ outf,
                                                 const float* __restrict__ resid) {
    __shared__ __align__(16) bf16 Bld[32 * 200];
    const int K = C_DIM;
    int n0 = blockIdx.x * 32;
    int m0 = blockIdx.y * 64;
    int t = threadIdx.x;
    {
        int h = t >> 5, nl = t & 31;
        int n = n0 + nl;
        float acc[24];
        for (int j = 0; j < 24; ++j) acc[j] = 0.f;
        float l = 0.f;
        for (int s = 0; s < NSPLIT; ++s) {
            const bf16* row = opart + ((size_t)(s * 8 + h) * N_PIX + n) * 24;
            bf16x8 a = *(const bf16x8*)(row);
            bf16x8 b = *(const bf16x8*)(row + 8);
            bf16x8 c = *(const bf16x8*)(row + 16);
            for (int j = 0; j < 8; ++j) {
                acc[j] += (float)a[j];
                acc[8 + j] += (float)b[j];
                acc[16 + j] += (float)c[j];
            }
            l += (float)lpart[(size_t)(s * 8 + h) * N_PIX + n];
        }
        float inv = 1.0f / l;
        bf16* dst = Bld + nl * 200 + h * 24;
        for (int g = 0; g < 3; ++g) {
            bf16x8 w;
            for (int j = 0; j < 8; ++j) w[j] = (bf16)(acc[g * 8 + j] * inv);
            *(bf16x8*)(dst + g * 8) = w;
        }
    }
    __syncthreads();
    int wave = t >> 6, lane = t & 63;
    int l16 = lane & 15, quad = lane >> 4;
    int mrow = m0 + wave * 16;
    float rv[8];
    for (int j = 0; j < 2; ++j)
        for (int r = 0; r < 4; ++r)
            rv[j * 4 + r] = resid[(size_t)(mrow + quad * 4 + r) * N_PIX + n0 + j * 16 + l16];
    f32x4 acc2[2] = {};
    for (int kk = 0; kk < K; kk += 32) {
        const f32x4* ar = (const f32x4*)(wproj + (mrow + l16) * K + kk + quad * 8);
        f32x4 wa = ar[0], wb = ar[1];
        bf16x8 a;
        for (int j = 0; j < 4; ++j) { a[j] = (bf16)wa[j]; a[4 + j] = (bf16)wb[j]; }
        bf16x8 b0 = *(const bf16x8*)(Bld + l16 * 200 + kk + quad * 8);
        bf16x8 b1 = *(const bf16x8*)(Bld + (16 + l16) * 200 + kk + quad * 8);
        acc2[0] = mfma16(a, b0, acc2[0]);
        acc2[1] = mfma16(a, b1, acc2[1]);
    }
    for (int j = 0; j < 2; ++j)
        for (int r = 0; r < 4; ++r) {
            int row = mrow + quad * 4 + r;
            int col = n0 + j * 16 + l16;
            outf[(size_t)row * N_PIX + col] = acc2[j][r] + rv[j * 4 + r];
        }
}

extern "C" void kernel_launch(void* const* d_in, const int* in_sizes, int n_in,
                              void* d_out, int out_size, void* d_ws, size_t ws_size,
                              hipStream_t stream) {
    const float* x     = (const float*)d_in[0];
    const float* gamma = (const float*)d_in[1];
    const float* beta  = (const float*)d_in[2];
    const float* wqkv  = (const float*)d_in[3];
    const float* wdw   = (const float*)d_in[4];
    const float* bdw   = (const float*)d_in[5];
    const float* wproj = (const float*)d_in[6];
    const float* temp  = (const float*)d_in[7];
    float* out = (float*)d_out;

    char* ws = (char*)d_ws;
    bf16* qkv     = (bf16*)(ws + 0);          // 576*4096*2 = 4718592
    bf16* qt      = (bf16*)(ws + 4718592);    // 2097152
    bf16* kt      = (bf16*)(ws + 6815744);    // 2097152
    bf16* vl      = (bf16*)(ws + 8912896);    // 2097152
    bf16* opart   = (bf16*)(ws + 11010048);   // 8*8*4096*24*2 = 12582912
    bf16* lpart   = (bf16*)(ws + 23592960);   // 8*8*4096*2 = 524288
    float* maxk2  = (float*)(ws + 24117248);  // 32

    ln_qkv<<<dim3(64, 9), 256, 0, stream>>>(x, gamma, beta, wqkv, qkv, maxk2);
    dwconv<<<1536, 256, 0, stream>>>(qkv, wdw, bdw, qt, kt, vl, maxk2);
    flash_attn<<<NSPLIT * 128, 256, 0, stream>>>(qt, kt, vl, temp, maxk2, opart, lpart);
    gemm_proj<<<dim3(128, 3), 256, 0, stream>>>(wproj, opart, lpart, out, x);
}